// Round 2
// baseline (3199.408 us; speedup 1.0000x reference)
//
#include <hip/hip_runtime.h>

typedef _Float16 half8_t __attribute__((ext_vector_type(8)));
typedef float    f32x4   __attribute__((ext_vector_type(4)));

#define T_STEPS 1024
#define BATCH   128
#define HID     128
#define GATES   512
#define STACK   1024
#define NG      8      // row groups of 16
#define RPG     16     // rows per group
#define RX_SLOT 32768  // 512 gate-rows x 16 rows f32
#define RH_SLOT 8192   // 16 rows x 128 units tagged u32
#define VROW    272    // LDS B-tile row stride (17*16B, slot-swizzled)
#define VBUF    4352   // 16*VROW

__device__ __forceinline__ float sigf(float x)     { return 1.0f / (1.0f + __expf(-x)); }
__device__ __forceinline__ float tanhfast(float x) { return 1.0f - 2.0f / (1.0f + __expf(2.0f * x)); }
__device__ __forceinline__ unsigned ldu(const unsigned* p) {
    return __hip_atomic_load(p, __ATOMIC_RELAXED, __HIP_MEMORY_SCOPE_AGENT);
}
__device__ __forceinline__ void stu(unsigned* p, unsigned v) {
    __hip_atomic_store(p, v, __ATOMIC_RELAXED, __HIP_MEMORY_SCOPE_AGENT);
}
__device__ __forceinline__ float ldf(const float* p) {
    return __hip_atomic_load(p, __ATOMIC_RELAXED, __HIP_MEMORY_SCOPE_AGENT);
}
__device__ __forceinline__ void stfa(float* p, float v) {
    __hip_atomic_store(p, v, __ATOMIC_RELAXED, __HIP_MEMORY_SCOPE_AGENT);
}

// 32 blocks = 4 types x 8 row-groups. type: 0=X0 (W_ih^0*x), 1=H0 (W_hh^0*h0 +
// epilogue), 2=X1 (W_ih^1*h0), 3=H1 (W_hh^1*h1 + epilogue + out). Only the
// H-cores carry the recurrence (128 MFMAs/step); X-cores are feed-forward and
// run ahead, streaming f32 gate-partials through watermark-gated rings.
// h0 crosses H0->X1 via in-band-tagged u32 words (proven protocol).
// B-tiles: 16 batch rows in LDS, 16B-slot XOR swizzle (slot ^ (row&7)).
__launch_bounds__(512, 2)
__global__ void stack_lstm_split(const float* __restrict__ inputs,
                                 const int*   __restrict__ ops,
                                 const float* __restrict__ w_ih,
                                 const float* __restrict__ w_hh,
                                 const float* __restrict__ b_ih,
                                 const float* __restrict__ b_hh,
                                 float* __restrict__ out,
                                 unsigned* __restrict__ wm,
                                 char* __restrict__ rx0,
                                 char* __restrict__ rx1,
                                 char* __restrict__ rh0,
                                 int D)
{
    const int bx   = blockIdx.x;
    const int type = bx >> 3;
    const int g    = bx & 7;
    const int tid  = threadIdx.x;
    const int wv   = tid >> 6;
    const int ln   = tid & 63;
    const int ml   = ln & 15;
    const int kg   = ln >> 4;
    const int mask = D - 1;

    __shared__ __align__(16) unsigned char vb[2 * VBUF];
    __shared__ unsigned ops_bits[512];  // 1024 steps x 16 rows, 1 bit each

    unsigned* pwm0 = wm + (0 * 8 + g) * 16;  // RX0 producer watermark
    unsigned* cwm0 = wm + (1 * 8 + g) * 16;  // RX0 consumer watermark
    unsigned* pwm1 = wm + (2 * 8 + g) * 16;  // RX1 producer
    unsigned* cwm1 = wm + (3 * 8 + g) * 16;  // RX1 consumer
    unsigned* cwmh = wm + (4 * 8 + g) * 16;  // RH0 consumer

    char* rhg = rh0 + (size_t)g * D * RH_SLOT;
    const f32x4 zz = {0.f, 0.f, 0.f, 0.f};

    if ((type & 1) == 0) {
        // ======================= X-core (feed-forward) =======================
        const int xlayer = type >> 1;
        char* rxg = ((xlayer == 0) ? rx0 : rx1) + (size_t)g * D * RX_SLOT;
        // A fragments: plain tiles j, rows 64wv+16j+ml, K=128 (w_ih cols)
        half8_t wf[16];
#pragma unroll
        for (int j = 0; j < 4; ++j) {
            const float* rowp = w_ih + (size_t)(xlayer * GATES + 64 * wv + 16 * j + ml) * HID;
#pragma unroll
            for (int kc = 0; kc < 4; ++kc) {
                const float* src = rowp + 32 * kc + 8 * kg;
                half8_t h;
#pragma unroll
                for (int q = 0; q < 8; q += 2) {
                    float2 f = *reinterpret_cast<const float2*>(src + q);
                    h[q] = (_Float16)f.x; h[q + 1] = (_Float16)f.y;
                }
                wf[j * 4 + kc] = h;
            }
        }
        const int row = tid >> 5;  // staging lane map: 16 rows x 32 cols
        const int c   = tid & 31;  // units 4c..4c+3
        const int sw  = ((c >> 1) ^ (row & 7)) << 4;  // slot-swizzled 16B slot
        const int sb8 = (c & 1) << 3;
        // prologue: stage vbuf[0]
        if (xlayer == 0) {
            float4 v = *reinterpret_cast<const float4*>(
                inputs + (size_t)(g * RPG + row) * HID + c * 4);
            unsigned lo = (unsigned)__builtin_bit_cast(unsigned short, (_Float16)v.x)
                        | ((unsigned)__builtin_bit_cast(unsigned short, (_Float16)v.y) << 16);
            unsigned hi = (unsigned)__builtin_bit_cast(unsigned short, (_Float16)v.z)
                        | ((unsigned)__builtin_bit_cast(unsigned short, (_Float16)v.w) << 16);
            *reinterpret_cast<unsigned long long*>(vb + row * VROW + sw + sb8)
                = (unsigned long long)lo | ((unsigned long long)hi << 32);
        } else {
            const unsigned* sp = (const unsigned*)rhg + row * HID + c * 4;  // slot 0
            unsigned b0, b1, b2, b3;
            for (;;) {
                b0 = ldu(sp); b1 = ldu(sp + 1); b2 = ldu(sp + 2); b3 = ldu(sp + 3);
                if ((((b0 ^ 1u) | (b1 ^ 1u) | (b2 ^ 1u) | (b3 ^ 1u)) & 0xFFFFu) == 0u) break;
                __builtin_amdgcn_s_sleep(1);
            }
            unsigned lo = (b0 >> 16) | (b1 & 0xFFFF0000u);
            unsigned hi = (b2 >> 16) | (b3 & 0xFFFF0000u);
            *reinterpret_cast<unsigned long long*>(vb + row * VROW + sw + sb8)
                = (unsigned long long)lo | ((unsigned long long)hi << 32);
        }
        __syncthreads();

        unsigned* pwm = (xlayer == 0) ? pwm0 : pwm1;
        unsigned* cwp = (xlayer == 0) ? cwm0 : cwm1;
        unsigned cw_seen = 0;

        for (int t = 0; t < T_STEPS; ++t) {
            // delayed-release publish: previous step's barrier drained vmcnt,
            // so slots <= t-1 are globally visible.
            if (tid == 0) {
                if (t > 0) stu(pwm, (unsigned)t);
                if (xlayer == 1) stu(cwmh, (unsigned)t);  // RH0 consumption
            }
            // ring backpressure (consumer must have freed slot t-D)
            {
                int need = t - D + 1;
                if (need > 0) {
                    while ((int)cw_seen < need) {
                        cw_seen = ldu(cwp);
                        if ((int)cw_seen < need) __builtin_amdgcn_s_sleep(2);
                    }
                }
            }
            // spec input for t+1 (hidden under this step's compute)
            float4 xn = {0.f, 0.f, 0.f, 0.f};
            unsigned b0 = 0, b1 = 0, b2 = 0, b3 = 0;
            const bool more = (t + 1 < T_STEPS);
            if (more) {
                if (xlayer == 0) {
                    xn = *reinterpret_cast<const float4*>(
                        inputs + ((size_t)(t + 1) * BATCH + g * RPG + row) * HID + c * 4);
                } else {
                    const unsigned* sp = (const unsigned*)(rhg + (size_t)((t + 1) & mask) * RH_SLOT)
                                       + row * HID + c * 4;
                    b0 = ldu(sp); b1 = ldu(sp + 1); b2 = ldu(sp + 2); b3 = ldu(sp + 3);
                }
            }
            // matvec: 16 MFMAs, 16 batch rows in B columns
            f32x4 acc[4] = {zz, zz, zz, zz};
            const unsigned char* vr = vb + (t & 1) * VBUF + ml * VROW;
#pragma unroll
            for (int kc = 0; kc < 4; ++kc) {
                const half8_t b = *reinterpret_cast<const half8_t*>(
                    vr + (((4 * kc + kg) ^ (ml & 7)) << 4));
                acc[0] = __builtin_amdgcn_mfma_f32_16x16x32_f16(wf[kc],      b, acc[0], 0, 0, 0);
                acc[1] = __builtin_amdgcn_mfma_f32_16x16x32_f16(wf[4 + kc],  b, acc[1], 0, 0, 0);
                acc[2] = __builtin_amdgcn_mfma_f32_16x16x32_f16(wf[8 + kc],  b, acc[2], 0, 0, 0);
                acc[3] = __builtin_amdgcn_mfma_f32_16x16x32_f16(wf[12 + kc], b, acc[3], 0, 0, 0);
            }
            // gate-partial stores (C row 4kg+r = gate-row 64wv+16j+4kg+r)
            char* px = rxg + (size_t)(t & mask) * RX_SLOT;
#pragma unroll
            for (int j = 0; j < 4; ++j)
#pragma unroll
                for (int r = 0; r < 4; ++r)
                    stfa((float*)(px + (size_t)(64 * wv + 16 * j + 4 * kg + r) * 64 + ml * 4),
                         acc[j][r]);
            // stage vbuf for t+1
            if (more) {
                unsigned lo, hi;
                if (xlayer == 0) {
                    lo = (unsigned)__builtin_bit_cast(unsigned short, (_Float16)xn.x)
                       | ((unsigned)__builtin_bit_cast(unsigned short, (_Float16)xn.y) << 16);
                    hi = (unsigned)__builtin_bit_cast(unsigned short, (_Float16)xn.z)
                       | ((unsigned)__builtin_bit_cast(unsigned short, (_Float16)xn.w) << 16);
                } else {
                    const unsigned ex = (unsigned)((t + 2) & 0xFFFF);
                    while ((((b0 ^ ex) | (b1 ^ ex) | (b2 ^ ex) | (b3 ^ ex)) & 0xFFFFu) != 0u) {
                        __builtin_amdgcn_s_sleep(1);
                        const unsigned* sp = (const unsigned*)(rhg + (size_t)((t + 1) & mask) * RH_SLOT)
                                           + row * HID + c * 4;
                        b0 = ldu(sp); b1 = ldu(sp + 1); b2 = ldu(sp + 2); b3 = ldu(sp + 3);
                    }
                    lo = (b0 >> 16) | (b1 & 0xFFFF0000u);
                    hi = (b2 >> 16) | (b3 & 0xFFFF0000u);
                }
                *reinterpret_cast<unsigned long long*>(
                    vb + ((t + 1) & 1) * VBUF + row * VROW + sw + sb8)
                    = (unsigned long long)lo | ((unsigned long long)hi << 32);
            }
            // drain (wave-level release for the px stores) + barrier
            asm volatile("s_waitcnt vmcnt(0) lgkmcnt(0)\n\ts_barrier" ::: "memory");
        }
        if (tid == 0) stu(pwm, (unsigned)T_STEPS);  // tail publish (last slots)
    } else {
        // ======================= H-core (recurrent) =========================
        const int hlayer = type >> 1;  // 1->0, 3->1
        const char* rxs = ((hlayer == 0) ? rx0 : rx1) + (size_t)g * D * RX_SLOT;
        // A fragments: gate-interleaved rows, K=128 (w_hh cols).
        // Acc tile i reg r at lane (ml,kg) = gate r of unit 16wv+4i+kg, row ml.
        half8_t wf[16];
#pragma unroll
        for (int i = 0; i < 4; ++i) {
            const int R = 128 * (ml & 3) + 16 * wv + 4 * i + (ml >> 2);
            const float* rowp = w_hh + (size_t)(hlayer * GATES + R) * HID;
#pragma unroll
            for (int kc = 0; kc < 4; ++kc) {
                const float* src = rowp + 32 * kc + 8 * kg;
                half8_t h;
#pragma unroll
                for (int q = 0; q < 8; q += 2) {
                    float2 f = *reinterpret_cast<const float2*>(src + q);
                    h[q] = (_Float16)f.x; h[q + 1] = (_Float16)f.y;
                }
                wf[i * 4 + kc] = h;
            }
        }
        float Bb[16];
#pragma unroll
        for (int i = 0; i < 4; ++i)
#pragma unroll
            for (int r = 0; r < 4; ++r) {
                const int R = 128 * r + 16 * wv + 4 * i + kg;
                Bb[i * 4 + r] = b_ih[hlayer * GATES + R] + b_hh[hlayer * GATES + R];
            }
        // ops bit-pack: word k covers t=2k..2k+1 x 16 rows
        {
            unsigned wbits = 0;
            for (int b = 0; b < 32; ++b) {
                const int tt = (tid << 1) + (b >> 4);
                const int rr = b & 15;
                wbits |= (unsigned)(ops[(size_t)tt * BATCH + g * RPG + rr] & 1) << b;
            }
            ops_bits[tid] = wbits;
        }
        // zero h(0) buffer
        for (int k = tid; k < VBUF / 4; k += 512)
            reinterpret_cast<unsigned*>(vb)[k] = 0u;

        unsigned* pwms = (hlayer == 0) ? pwm0 : pwm1;
        unsigned* cwmm = (hlayer == 0) ? cwm0 : cwm1;
        unsigned wm_seen = 0;
        while (wm_seen < 1u) {
            wm_seen = ldu(pwms);
            if (wm_seen < 1u) __builtin_amdgcn_s_sleep(1);
        }
        float pr[16];
        {
            const char* sb = rxs + ((16 * wv + kg) << 6) + (ml << 2);  // slot 0
#pragma unroll
            for (int i = 0; i < 4; ++i)
#pragma unroll
                for (int r = 0; r < 4; ++r)
                    pr[i * 4 + r] = ldf((const float*)(sb + r * 8192 + i * 256));
        }
        float c_cur[4] = {0.f, 0.f, 0.f, 0.f};
        float h_top[4] = {0.f, 0.f, 0.f, 0.f};
        int pos = 0;
        unsigned ch_seen = 0;
        __syncthreads();

        for (int t = 0; t < T_STEPS; ++t) {
            unsigned wm_ld = ldu(pwms);  // pipelined watermark read
            if (type == 1) {             // RH0 producer backpressure
                int need = t - D + 1;
                if (need > 0) {
                    while ((int)ch_seen < need) {
                        ch_seen = ldu(cwmh);
                        if ((int)ch_seen < need) __builtin_amdgcn_s_sleep(2);
                    }
                }
            }
            // recurrent matvec on h (16 MFMAs)
            f32x4 acc[4] = {zz, zz, zz, zz};
            const unsigned char* vr = vb + (t & 1) * VBUF + ml * VROW;
#pragma unroll
            for (int kc = 0; kc < 4; ++kc) {
                const half8_t b = *reinterpret_cast<const half8_t*>(
                    vr + (((4 * kc + kg) ^ (ml & 7)) << 4));
                acc[0] = __builtin_amdgcn_mfma_f32_16x16x32_f16(wf[kc],      b, acc[0], 0, 0, 0);
                acc[1] = __builtin_amdgcn_mfma_f32_16x16x32_f16(wf[4 + kc],  b, acc[1], 0, 0, 0);
                acc[2] = __builtin_amdgcn_mfma_f32_16x16x32_f16(wf[8 + kc],  b, acc[2], 0, 0, 0);
                acc[3] = __builtin_amdgcn_mfma_f32_16x16x32_f16(wf[12 + kc], b, acc[3], 0, 0, 0);
            }
            // lane-local epilogue: 4 (row=ml, unit) pairs, all 4 gates in regs
            const unsigned opw = ops_bits[t >> 1];
            const int op = (int)((opw >> (((t & 1) << 4) + ml)) & 1u);
            unsigned char* vw = vb + ((t + 1) & 1) * VBUF + ml * VROW;
#pragma unroll
            for (int i = 0; i < 4; ++i) {
                const float gi = acc[i][0] + pr[i * 4 + 0] + Bb[i * 4 + 0];
                const float gf = acc[i][1] + pr[i * 4 + 1] + Bb[i * 4 + 1];
                const float gg = acc[i][2] + pr[i * 4 + 2] + Bb[i * 4 + 2];
                const float go = acc[i][3] + pr[i * 4 + 3] + Bb[i * 4 + 3];
                const float cn = sigf(gf) * c_cur[i] + sigf(gi) * tanhfast(gg);
                const float hn = sigf(go) * tanhfast(cn);
                const float hs = op ? hn : h_top[i];
                c_cur[i] = op ? cn : c_cur[i];
                h_top[i] = hs;
                const int u = 16 * wv + 4 * i + kg;
                *reinterpret_cast<_Float16*>(
                    vw + (((u >> 3) ^ (ml & 7)) << 4) + ((u & 7) << 1)) = (_Float16)hs;
                if (type == 1) {
                    const unsigned short hx = __builtin_bit_cast(unsigned short, (_Float16)hn);
                    stu((unsigned*)(rhg + (size_t)(t & mask) * RH_SLOT) + (ml * HID + u),
                        ((unsigned)hx << 16) | (unsigned)((t + 1) & 0xFFFF));
                } else {
                    out[(size_t)(pos + 1) * BATCH * HID + (size_t)(g * RPG + ml) * HID + u] = hn;
                }
            }
            pos += op;
            if (tid == 0) stu(cwmm, (unsigned)t);  // free slots <= t-1
            // spec gate-partials for t+1
            if (t + 1 < T_STEPS) {
                if (wm_seen < wm_ld) wm_seen = wm_ld;
                const unsigned needw = (unsigned)(t + 2);
                while (wm_seen < needw) {
                    wm_seen = ldu(pwms);
                    if (wm_seen < needw) __builtin_amdgcn_s_sleep(1);
                }
                const char* sb = rxs + (size_t)((t + 1) & mask) * RX_SLOT
                               + ((16 * wv + kg) << 6) + (ml << 2);
#pragma unroll
                for (int i = 0; i < 4; ++i)
#pragma unroll
                    for (int r = 0; r < 4; ++r)
                        pr[i * 4 + r] = ldf((const float*)(sb + r * 8192 + i * 256));
            }
            // LDS-drain barrier only: px spec loads / out / RH0 stores stay in flight
            asm volatile("s_waitcnt lgkmcnt(0)\n\ts_barrier" ::: "memory");
        }
        if (type == 3 && tid < RPG)
            out[(size_t)(STACK + 1) * BATCH * HID + g * RPG + tid] = (float)pos;
    }
}

extern "C" void kernel_launch(void* const* d_in, const int* in_sizes, int n_in,
                              void* d_out, int out_size, void* d_ws, size_t ws_size,
                              hipStream_t stream)
{
    (void)in_sizes; (void)n_in;
    const float* inputs = (const float*)d_in[0];
    const int*   ops    = (const int*)d_in[1];
    const float* w_ih   = (const float*)d_in[2];
    const float* w_hh   = (const float*)d_in[3];
    const float* b_ih   = (const float*)d_in[4];
    const float* b_hh   = (const float*)d_in[5];
    float* out = (float*)d_out;

    // ws: [0,4096) watermarks; then RX0 | RX1 | RH0 rings, D slots each.
    unsigned* wm = (unsigned*)d_ws;
    char* rx0 = (char*)d_ws + 4096;
    size_t perD = (size_t)NG * (2 * (size_t)RX_SLOT + RH_SLOT);  // 589824 B
    size_t avail = (ws_size > 4096) ? (ws_size - 4096) / perD : 0;
    int D = 4;  // protocol needs D >= 4
    while ((size_t)(D * 2) <= avail && D < 512) D *= 2;
    char* rx1 = rx0 + (size_t)NG * D * RX_SLOT;
    char* rh0 = rx1 + (size_t)NG * D * RX_SLOT;

    hipMemsetAsync(d_ws, 0, 4096, stream);   // zero watermarks each launch
    hipMemsetAsync(d_out, 0, (size_t)out_size * sizeof(float), stream);

    stack_lstm_split<<<dim3(32), dim3(512), 0, stream>>>(
        inputs, ops, w_ih, w_hh, b_ih, b_hh, out, wm, rx0, rx1, rh0, D);
}

// Round 3
// 2852.593 us; speedup vs baseline: 1.1216x; 1.1216x over previous
//
#include <hip/hip_runtime.h>

typedef _Float16 half8_t __attribute__((ext_vector_type(8)));
typedef float    f32x4   __attribute__((ext_vector_type(4)));

#define T_STEPS 1024
#define BATCH   128
#define HID     128
#define GATES   512
#define STACK   1024
#define NG      8      // batch groups of 16 rows
#define RPG     16     // rows per group

__device__ __forceinline__ float sigf(float x)     { return 1.0f / (1.0f + __expf(-x)); }
__device__ __forceinline__ float tanhfast(float x) { return 1.0f - 2.0f / (1.0f + __expf(2.0f * x)); }
__device__ __forceinline__ unsigned ldu(const unsigned* p) {
    return __hip_atomic_load(p, __ATOMIC_RELAXED, __HIP_MEMORY_SCOPE_AGENT);
}
__device__ __forceinline__ void stu(unsigned* p, unsigned v) {
    __hip_atomic_store(p, v, __ATOMIC_RELAXED, __HIP_MEMORY_SCOPE_AGENT);
}
__device__ __forceinline__ unsigned pack2(float a, float b) {
    return (unsigned)__builtin_bit_cast(unsigned short, (_Float16)a)
         | ((unsigned)__builtin_bit_cast(unsigned short, (_Float16)b) << 16);
}
// Swizzled vin byte address. Layout: [row 0..15][512 B = 256 k * f16].
// 16B slot index XOR'd with row&7. Rowstride 512B = 32 slots = 0 mod 8
// -> every aligned 8-lane group of a wave hits 8 distinct banks-quads
// (the round-2 failure was a 272B pad breaking exactly this congruence).
__device__ __forceinline__ int vaddr(int row, int kb) {
    const int slot = kb >> 4;
    return row * 512 + (((slot & 24) | ((slot ^ row) & 7)) << 4) + (kb & 15);
}

// grid = 16: block b -> layer = b>>3, group g = b&7 (rows g*16..g*16+15).
// Round-1 protocol (tagged u32 ring, relaxed agent atomics, cons watermark),
// but B-fragment columns carry 16 REAL batch rows instead of a broadcast:
// the same 256 MFMAs/step now serve 16 rows (16x less matrix-pipe work per row).
// A-rows gate-interleaved: acc tile i reg r at lane (ml,kg) = gate r of unit
// 16wv+4i+kg for batch row ml -> lane-local epilogue, no gate LDS round trip.
__launch_bounds__(512, 2)
__global__ void stack_lstm_b16(const float* __restrict__ inputs,
                               const int*   __restrict__ ops,
                               const float* __restrict__ w_ih,
                               const float* __restrict__ w_hh,
                               const float* __restrict__ b_ih,
                               const float* __restrict__ b_hh,
                               float* __restrict__ out,
                               unsigned* __restrict__ ring,  // [D][BATCH][HID] tagged
                               unsigned* __restrict__ cons,  // [NG*16] watermark
                               int D)                        // ring depth, pow2 >= 4
{
    const int bx    = blockIdx.x;
    const int layer = bx >> 3;
    const int g     = bx & 7;
    const int tid   = threadIdx.x;  // 0..511
    const int wv    = tid >> 6;
    const int ln    = tid & 63;
    const int ml    = ln & 15;      // C column = batch row within group
    const int kg    = ln >> 4;
    const int mask  = D - 1;

    __shared__ __align__(16) unsigned char vb[2][RPG * 512];  // [buf][row][k] f16
    __shared__ unsigned ops_bits[512];  // word p: steps 2p,2p+1 x 16 rows

    // ---- A fragments, gate-interleaved rows, virtual K = [x-part | h-part]
    half8_t wf[32];
#pragma unroll
    for (int i = 0; i < 4; ++i) {
        const int R = 128 * (ml & 3) + 16 * wv + 4 * i + (ml >> 2);
        const float* rowi = w_ih + (size_t)(layer * GATES + R) * HID;
        const float* rowh = w_hh + (size_t)(layer * GATES + R) * HID;
#pragma unroll
        for (int kc = 0; kc < 8; ++kc) {
            const int k0 = 32 * kc + 8 * kg;
            const float* src = (kc < 4) ? (rowi + k0) : (rowh + (k0 - 128));
            half8_t h;
#pragma unroll
            for (int j = 0; j < 8; j += 2) {
                float2 f = *reinterpret_cast<const float2*>(src + j);
                h[j] = (_Float16)f.x; h[j + 1] = (_Float16)f.y;
            }
            wf[i * 8 + kc] = h;
        }
    }
    float Bb[16];
#pragma unroll
    for (int i = 0; i < 4; ++i)
#pragma unroll
        for (int r = 0; r < 4; ++r) {
            const int R = 128 * r + 16 * wv + 4 * i + kg;
            Bb[i * 4 + r] = b_ih[layer * GATES + R] + b_hh[layer * GATES + R];
        }

    // ---- ops bit-pack (vectorized int4 loads)
    {
        unsigned wbits = 0;
        const int* po = ops + (size_t)(tid * 2) * BATCH + g * RPG;
#pragma unroll
        for (int hh = 0; hh < 2; ++hh) {
            int v[16];
#pragma unroll
            for (int q = 0; q < 4; ++q) {
                int4 t4 = *reinterpret_cast<const int4*>(po + hh * BATCH + q * 4);
                v[q * 4 + 0] = t4.x; v[q * 4 + 1] = t4.y;
                v[q * 4 + 2] = t4.z; v[q * 4 + 3] = t4.w;
            }
#pragma unroll
            for (int j = 0; j < 16; ++j)
                wbits |= (unsigned)(v[j] & 1) << (hh * 16 + j);
        }
        ops_bits[tid] = wbits;
    }

    // ---- initial staging: vb[0] = [x/h0-part rows | h-part zeros]
    const int srow = tid >> 5, sc = tid & 31;  // 16 rows x 32 cols (4 k each)
    *reinterpret_cast<unsigned long long*>(&vb[0][vaddr(srow, 256 + sc * 8)]) = 0ull;
    if (layer == 0) {
        float4 v = *reinterpret_cast<const float4*>(
            inputs + (size_t)(g * RPG + srow) * HID + sc * 4);
        unsigned lo = pack2(v.x, v.y), hi = pack2(v.z, v.w);
        *reinterpret_cast<unsigned long long*>(&vb[0][vaddr(srow, sc * 8)])
            = (unsigned long long)lo | ((unsigned long long)hi << 32);
    } else {
        const unsigned* sp = ring + (size_t)(g * RPG + srow) * HID + sc * 4;
        unsigned s0, s1, s2, s3;
        for (;;) {
            s0 = ldu(sp); s1 = ldu(sp + 1); s2 = ldu(sp + 2); s3 = ldu(sp + 3);
            if ((((s0 ^ 1u) | (s1 ^ 1u) | (s2 ^ 1u) | (s3 ^ 1u)) & 0xFFFFu) == 0u) break;
            __builtin_amdgcn_s_sleep(1);
        }
        unsigned lo = (s0 >> 16) | (s1 & 0xFFFF0000u);
        unsigned hi = (s2 >> 16) | (s3 & 0xFFFF0000u);
        *reinterpret_cast<unsigned long long*>(&vb[0][vaddr(srow, sc * 8)])
            = (unsigned long long)lo | ((unsigned long long)hi << 32);
    }
    __syncthreads();

    // per-lane stack state for (row=ml, units 16wv+4i+kg)
    float c_cur[4] = {0.f, 0.f, 0.f, 0.f};
    float h_top[4] = {0.f, 0.f, 0.f, 0.f};
    int   pos = 0, cons_seen = 0;
    const int rb = (g * RPG + ml) * HID;  // ring/out row base for this lane

    for (int t = 0; t < T_STEPS; ++t) {
        const int buf = t & 1, nb = buf ^ 1;
        const bool more = (t + 1 < T_STEPS);

        // consumer watermark publish at step TOP: slot t was staged during
        // step t-1 and the barrier guarantees every poll finished -> no
        // thread can still be spinning on a slot once it becomes recyclable.
        if (layer == 1 && tid == 0 && t > 0)
            stu(cons + g * 16, (unsigned)t);

        // spec loads for t+1 (latency hidden under this step's MFMA)
        float4 xn = {0.f, 0.f, 0.f, 0.f};
        unsigned s0 = 0, s1 = 0, s2 = 0, s3 = 0;
        if (more) {
            if (layer == 0) {
                xn = *reinterpret_cast<const float4*>(
                    inputs + ((size_t)(t + 1) * BATCH + g * RPG + srow) * HID + sc * 4);
            } else {
                const unsigned* sp = ring + ((size_t)((t + 1) & mask) * BATCH
                                             + g * RPG + srow) * HID + sc * 4;
                s0 = ldu(sp); s1 = ldu(sp + 1); s2 = ldu(sp + 2); s3 = ldu(sp + 3);
            }
        }
        // L0 ring backpressure (before this step's slot-t stores)
        if (layer == 0 && t >= D) {
            const int need = t - D;
            while (cons_seen < need) {
                cons_seen = (int)ldu(cons + g * 16);
                if (cons_seen < need) __builtin_amdgcn_s_sleep(2);
            }
        }

        // ---- matvec: 32 MFMAs/wave, B columns = 16 batch rows
        f32x4 a0 = {0.f, 0.f, 0.f, 0.f}, a1 = a0, a2 = a0, a3 = a0;
        const unsigned char* vr = &vb[buf][0];
#pragma unroll
        for (int kc = 0; kc < 8; ++kc) {
            const int slot = 4 * kc + kg;
            const half8_t bfrag = *reinterpret_cast<const half8_t*>(
                vr + ml * 512 + (((slot & 24) | ((slot ^ ml) & 7)) << 4));
            a0 = __builtin_amdgcn_mfma_f32_16x16x32_f16(wf[kc],      bfrag, a0, 0, 0, 0);
            a1 = __builtin_amdgcn_mfma_f32_16x16x32_f16(wf[8 + kc],  bfrag, a1, 0, 0, 0);
            a2 = __builtin_amdgcn_mfma_f32_16x16x32_f16(wf[16 + kc], bfrag, a2, 0, 0, 0);
            a3 = __builtin_amdgcn_mfma_f32_16x16x32_f16(wf[24 + kc], bfrag, a3, 0, 0, 0);
        }

        // ---- lane-local epilogue: 4 units of row ml, all 4 gates in regs
        const unsigned opw = ops_bits[t >> 1];
        const int op = (int)((opw >> (((t & 1) << 4) + ml)) & 1u);
        const f32x4 av[4] = {a0, a1, a2, a3};
#pragma unroll
        for (int i = 0; i < 4; ++i) {
            const float gi = av[i][0] + Bb[i * 4 + 0];
            const float gf = av[i][1] + Bb[i * 4 + 1];
            const float gg = av[i][2] + Bb[i * 4 + 2];
            const float go = av[i][3] + Bb[i * 4 + 3];
            const float cn = sigf(gf) * c_cur[i] + sigf(gi) * tanhfast(gg);
            const float hn = sigf(go) * tanhfast(cn);
            const float hs = op ? hn : h_top[i];
            c_cur[i] = op ? cn : c_cur[i];
            h_top[i] = hs;
            const int u = 16 * wv + 4 * i + kg;
            // recurrent h into next buffer (stack-selected value)
            *reinterpret_cast<_Float16*>(&vb[nb][vaddr(ml, 256 + 2 * u)]) = (_Float16)hs;
            if (layer == 0) {
                const unsigned short hx = __builtin_bit_cast(unsigned short, (_Float16)hn);
                stu(ring + (size_t)(t & mask) * BATCH * HID + rb + u,
                    ((unsigned)hx << 16) | (unsigned)((t + 1) & 0xFFFF));
            } else {
                out[(size_t)(pos + 1) * BATCH * HID + rb + u] = hn;
            }
        }
        pos += op;

        // ---- stage next step's x/h0-part
        if (more) {
            unsigned lo, hi;
            if (layer == 0) {
                lo = pack2(xn.x, xn.y); hi = pack2(xn.z, xn.w);
            } else {
                const unsigned ex = (unsigned)((t + 2) & 0xFFFF);
                while ((((s0 ^ ex) | (s1 ^ ex) | (s2 ^ ex) | (s3 ^ ex)) & 0xFFFFu) != 0u) {
                    __builtin_amdgcn_s_sleep(1);
                    const unsigned* sp = ring + ((size_t)((t + 1) & mask) * BATCH
                                                 + g * RPG + srow) * HID + sc * 4;
                    s0 = ldu(sp); s1 = ldu(sp + 1); s2 = ldu(sp + 2); s3 = ldu(sp + 3);
                }
                lo = (s0 >> 16) | (s1 & 0xFFFF0000u);
                hi = (s2 >> 16) | (s3 & 0xFFFF0000u);
            }
            *reinterpret_cast<unsigned long long*>(&vb[nb][vaddr(srow, sc * 8)])
                = (unsigned long long)lo | ((unsigned long long)hi << 32);
        }

        // LDS-drain barrier only: ring/out stores and spec loads stay in flight
        asm volatile("s_waitcnt lgkmcnt(0)\n\ts_barrier" ::: "memory");
    }

    // final pos per row (threads 0..15 have wv=0,kg=0,ml=tid -> own row tid)
    if (layer == 1 && tid < RPG)
        out[(size_t)(STACK + 1) * BATCH * HID + g * RPG + tid] = (float)pos;
}

extern "C" void kernel_launch(void* const* d_in, const int* in_sizes, int n_in,
                              void* d_out, int out_size, void* d_ws, size_t ws_size,
                              hipStream_t stream)
{
    (void)in_sizes; (void)n_in;
    const float* inputs = (const float*)d_in[0];
    const int*   ops    = (const int*)d_in[1];
    const float* w_ih   = (const float*)d_in[2];
    const float* w_hh   = (const float*)d_in[3];
    const float* b_ih   = (const float*)d_in[4];
    const float* b_hh   = (const float*)d_in[5];
    float* out = (float*)d_out;

    // ws layout: [0,4096) cons watermarks, then tagged u32 ring [D][128][128]
    unsigned* cons = (unsigned*)d_ws;
    unsigned* ring = (unsigned*)((char*)d_ws + 4096);

    size_t slot_bytes = (size_t)BATCH * HID * sizeof(unsigned);  // 64 KiB
    size_t avail = (ws_size > 4096) ? (ws_size - 4096) / slot_bytes : 4;
    int D = 4;  // protocol needs D >= 4 (lag <= 2 + slack)
    while ((size_t)(D * 2) <= avail && D < T_STEPS) D *= 2;

    hipMemsetAsync(d_ws, 0, 4096, stream);  // zero watermarks
    hipMemsetAsync(d_out, 0, (size_t)out_size * sizeof(float), stream);

    stack_lstm_b16<<<dim3(16), dim3(512), 0, stream>>>(
        inputs, ops, w_ih, w_hh, b_ih, b_hh, out, ring, cons, D);
}

// Round 4
// 1151.174 us; speedup vs baseline: 2.7793x; 2.4780x over previous
//
#include <hip/hip_runtime.h>

typedef _Float16 half8_t __attribute__((ext_vector_type(8)));
typedef float    f32x4   __attribute__((ext_vector_type(4)));

#define T_STEPS 1024
#define BATCH   128
#define HID     128
#define GATES   512
#define STACK   1024

__device__ __forceinline__ float sigf(float x)     { return 1.0f / (1.0f + __expf(-x)); }
__device__ __forceinline__ float tanhfast(float x) { return 1.0f - 2.0f / (1.0f + __expf(2.0f * x)); }
__device__ __forceinline__ unsigned ldu(const unsigned* p) {
    return __hip_atomic_load(p, __ATOMIC_RELAXED, __HIP_MEMORY_SCOPE_AGENT);
}
__device__ __forceinline__ void stu(unsigned* p, unsigned v) {
    __hip_atomic_store(p, v, __ATOMIC_RELAXED, __HIP_MEMORY_SCOPE_AGENT);
}

// grid = 256: blocks [0,128) = layer 0 of row r, [128,256) = layer 1 of row r.
// Round-1 structure (1 row/block, gate-interleaved A-rows, lane-local epilogue,
// tagged u32 ring, lgkm-only barrier) + two serial-path cuts:
//  (1) cross-step pipelining: x-part MFMAs (K-chunks 0-3, feed-forward) for
//      step t+1 run DURING step t into accumulator N, overlapping the epilogue;
//      only the h-part (K-chunks 4-7) is on the recurrent critical path.
//      Accumulation order per gate row is unchanged (kc 0..3 then 4..7) ->
//      bitwise-identical results to round 1.
//  (2) lead-builder: L1 waits at start until L0 is min(D-1,8) slots ahead, and
//      spec-loads slot t+2 at step-t top. Equilibrium lead >= 3 keeps the
//      cross-XCD store->load latency OFF the per-step critical path.
__launch_bounds__(512, 2)
__global__ void stack_lstm_pipe2(const float* __restrict__ inputs,
                                 const int*   __restrict__ ops,
                                 const float* __restrict__ w_ih,
                                 const float* __restrict__ w_hh,
                                 const float* __restrict__ b_ih,
                                 const float* __restrict__ b_hh,
                                 float* __restrict__ out,
                                 unsigned* __restrict__ ring,  // [D][BATCH][HID]
                                 unsigned* __restrict__ consw, // [BATCH] watermark
                                 int D)                        // ring depth, pow2 >= 4
{
    const int bx    = blockIdx.x;
    const int layer = bx >> 7;      // 0 or 1
    const int r     = bx & 127;     // batch row
    const int tid   = threadIdx.x;  // 0..511
    const int wv    = tid >> 6;     // wave 0..7
    const int ln    = tid & 63;
    const int ml    = ln & 15;
    const int kg    = ln >> 4;
    const int isel  = ml >> 2;
    const int unit  = 16 * wv + 4 * isel + kg;
    const bool uw   = ((ml & 3) == 0);
    const int mask  = D - 1;

    __shared__ __align__(16) _Float16 vbx[2][HID];  // x-input for step parity p
    __shared__ __align__(16) _Float16 vbh[2][HID];  // h written end of step p^1
    __shared__ int ops_s[T_STEPS];

    // ---- weights as MFMA A-fragments, gate-interleaved rows (round-1 layout)
    half8_t wf[32];  // [i*8 + kc], kc 0..3 = w_ih cols, 4..7 = w_hh cols
#pragma unroll
    for (int i = 0; i < 4; ++i) {
        const int R = 128 * (ml & 3) + 16 * wv + 4 * i + (ml >> 2);
        const float* rowi = w_ih + (size_t)(layer * GATES + R) * HID;
        const float* rowh = w_hh + (size_t)(layer * GATES + R) * HID;
#pragma unroll
        for (int kc = 0; kc < 8; ++kc) {
            const int k0 = 32 * kc + 8 * kg;
            const float* src = (kc < 4) ? (rowi + k0) : (rowh + (k0 - 128));
            half8_t h;
#pragma unroll
            for (int j = 0; j < 8; j += 2) {
                float2 f = *reinterpret_cast<const float2*>(src + j);
                h[j] = (_Float16)f.x; h[j + 1] = (_Float16)f.y;
            }
            wf[i * 8 + kc] = h;
        }
    }
    float Bb[4];
#pragma unroll
    for (int g = 0; g < 4; ++g)
        Bb[g] = b_ih[layer * GATES + 128 * g + unit] + b_hh[layer * GATES + 128 * g + unit];

    ops_s[tid]       = ops[(size_t)tid * BATCH + r];
    ops_s[tid + 512] = ops[(size_t)(tid + 512) * BATCH + r];

    const bool stager = (tid >= 128 && tid < 256);
    const int  su     = tid - 128;

    float c_cur = 0.f, h_top = 0.f;
    int   pos = 0, cons_seen = 0;
    float xs0 = 0.f;  // L0 stagers: holds x(t+2) entering step t

    // ---- lead-builder: L1 starts only once L0 has produced slot lead-1
    if (layer == 1 && tid == 0) {
        int lead = D - 1; if (lead > 8) lead = 8;  // >= 3 (D >= 4)
        const unsigned* p0 = ring + (size_t)((lead - 1) & mask) * BATCH * HID
                                  + (size_t)r * HID;
        while (((ldu(p0) ^ (unsigned)lead) & 0xFFFFu) != 0u)
            __builtin_amdgcn_s_sleep(8);
    }

    // ---- prologue staging: vbx[0]=in(0), vbx[1]=in(1); vbh[0]=0
    if (stager) {
        if (layer == 0) {
            vbx[0][su] = (_Float16)inputs[(size_t)r * HID + su];
            vbx[1][su] = (_Float16)inputs[(size_t)BATCH * HID + (size_t)r * HID + su];
            xs0 = inputs[(size_t)(2 * BATCH) * HID + (size_t)r * HID + su];  // x(2)
        } else {
#pragma unroll
            for (int s = 0; s < 2; ++s) {
                const unsigned* sp = ring + (size_t)s * BATCH * HID + (size_t)r * HID + su;
                const unsigned ex = (unsigned)(s + 1);
                unsigned v;
                do {
                    v = ldu(sp);
                    if (((v ^ ex) & 0xFFFFu) == 0u) break;
                    __builtin_amdgcn_s_sleep(1);
                } while (true);
                vbx[s][su] = __builtin_bit_cast(_Float16, (unsigned short)(v >> 16));
            }
        }
    }
    if (tid < HID) vbh[0][tid] = (_Float16)0.f;
    __syncthreads();

    // ---- A = x-part of step 0 (from vbx[0])
    f32x4 A[4], N[4];
    A[0] = f32x4{0.f, 0.f, 0.f, 0.f}; A[1] = A[0]; A[2] = A[0]; A[3] = A[0];
#pragma unroll
    for (int kc = 0; kc < 4; ++kc) {
        const half8_t xb = *reinterpret_cast<const half8_t*>(&vbx[0][32 * kc + 8 * kg]);
        A[0] = __builtin_amdgcn_mfma_f32_16x16x32_f16(wf[kc],      xb, A[0], 0, 0, 0);
        A[1] = __builtin_amdgcn_mfma_f32_16x16x32_f16(wf[8 + kc],  xb, A[1], 0, 0, 0);
        A[2] = __builtin_amdgcn_mfma_f32_16x16x32_f16(wf[16 + kc], xb, A[2], 0, 0, 0);
        A[3] = __builtin_amdgcn_mfma_f32_16x16x32_f16(wf[24 + kc], xb, A[3], 0, 0, 0);
    }
    __syncthreads();  // protect vbx[0] from step-0 staging until all read it

    auto step = [&](const int tt, const int PP, f32x4* AC, f32x4* AN) {
        // consumer watermark at step top (slot tt's reads ended 2 steps ago)
        if (layer == 1 && tid == 0 && tt > 0)
            stu(consw + r, (unsigned)tt);
        // spec loads for input(tt+2), latency hidden under this whole step
        unsigned sv = 0; float xnl = 0.f;
        const bool sp2 = (tt + 2 < T_STEPS);
        if (stager) {
            if (layer == 0) {
                if (tt + 3 < T_STEPS)
                    xnl = inputs[(size_t)(tt + 3) * BATCH * HID + (size_t)r * HID + su];
            } else if (sp2) {
                sv = ldu(ring + (size_t)((tt + 2) & mask) * BATCH * HID
                              + (size_t)r * HID + su);
            }
        }
        // ---- h-part (recurrent critical path): K-chunks 4..7 into AC
#pragma unroll
        for (int kc = 0; kc < 4; ++kc) {
            const half8_t hb = *reinterpret_cast<const half8_t*>(&vbh[PP][32 * kc + 8 * kg]);
            AC[0] = __builtin_amdgcn_mfma_f32_16x16x32_f16(wf[4 + kc],  hb, AC[0], 0, 0, 0);
            AC[1] = __builtin_amdgcn_mfma_f32_16x16x32_f16(wf[12 + kc], hb, AC[1], 0, 0, 0);
            AC[2] = __builtin_amdgcn_mfma_f32_16x16x32_f16(wf[20 + kc], hb, AC[2], 0, 0, 0);
            AC[3] = __builtin_amdgcn_mfma_f32_16x16x32_f16(wf[28 + kc], hb, AC[3], 0, 0, 0);
        }
        // ---- x-part for step tt+1 into AN (off the critical path)
        AN[0] = f32x4{0.f, 0.f, 0.f, 0.f}; AN[1] = AN[0]; AN[2] = AN[0]; AN[3] = AN[0];
#pragma unroll
        for (int kc = 0; kc < 4; ++kc) {
            const half8_t xb = *reinterpret_cast<const half8_t*>(&vbx[PP ^ 1][32 * kc + 8 * kg]);
            AN[0] = __builtin_amdgcn_mfma_f32_16x16x32_f16(wf[kc],      xb, AN[0], 0, 0, 0);
            AN[1] = __builtin_amdgcn_mfma_f32_16x16x32_f16(wf[8 + kc],  xb, AN[1], 0, 0, 0);
            AN[2] = __builtin_amdgcn_mfma_f32_16x16x32_f16(wf[16 + kc], xb, AN[2], 0, 0, 0);
            AN[3] = __builtin_amdgcn_mfma_f32_16x16x32_f16(wf[24 + kc], xb, AN[3], 0, 0, 0);
        }
        // ---- lane-local epilogue (round-1 layout: gv[reg] = gate reg of unit)
        const f32x4 s01 = (isel & 1) ? AC[1] : AC[0];
        const f32x4 s23 = (isel & 1) ? AC[3] : AC[2];
        const f32x4 gv  = (isel & 2) ? s23 : s01;
        const int   op  = ops_s[tt];
        const float cn = sigf(gv[1] + Bb[1]) * c_cur
                       + sigf(gv[0] + Bb[0]) * tanhfast(gv[2] + Bb[2]);
        const float hn = sigf(gv[3] + Bb[3]) * tanhfast(cn);
        const float hs = op ? hn : h_top;
        if (uw) {
            vbh[PP ^ 1][unit] = (_Float16)hs;
            if (layer == 0) {
                const unsigned short hx = __builtin_bit_cast(unsigned short, (_Float16)hn);
                if (D < T_STEPS && tt >= D) {  // ring backpressure (rare)
                    const int need = tt - D;
                    while (cons_seen < need) {
                        cons_seen = (int)ldu(consw + r);
                        if (cons_seen >= need) break;
                        __builtin_amdgcn_s_sleep(1);
                    }
                }
                stu(ring + (size_t)(tt & mask) * BATCH * HID + (size_t)r * HID + unit,
                    ((unsigned)hx << 16) | (unsigned)((tt + 1) & 0xFFFF));
            } else {
                out[(size_t)(pos + 1) * BATCH * HID + (size_t)r * HID + unit] = hn;
            }
        }
        h_top = hs;
        c_cur = op ? cn : c_cur;
        pos += op;
        // ---- stage vbx[PP] := input(tt+2)
        if (stager && sp2) {
            if (layer == 0) {
                vbx[PP][su] = (_Float16)xs0;
                xs0 = xnl;
            } else {
                unsigned v = sv;
                const unsigned ex = (unsigned)((tt + 3) & 0xFFFF);
                while (((v ^ ex) & 0xFFFFu) != 0u) {
                    __builtin_amdgcn_s_sleep(1);
                    v = ldu(ring + (size_t)((tt + 2) & mask) * BATCH * HID
                                 + (size_t)r * HID + su);
                }
                vbx[PP][su] = __builtin_bit_cast(_Float16, (unsigned short)(v >> 16));
            }
        }
        // LDS-drain barrier only; global loads/stores stay in flight
        asm volatile("s_waitcnt lgkmcnt(0)\n\ts_barrier" ::: "memory");
    };

    for (int t = 0; t < T_STEPS; t += 2) {
        step(t,     0, A, N);
        step(t + 1, 1, N, A);
    }

    // final pos (float32 — exact for ints <= 1024)
    if (layer == 1 && tid == 0)
        out[(size_t)(STACK + 1) * BATCH * HID + r] = (float)pos;
}

extern "C" void kernel_launch(void* const* d_in, const int* in_sizes, int n_in,
                              void* d_out, int out_size, void* d_ws, size_t ws_size,
                              hipStream_t stream)
{
    (void)in_sizes; (void)n_in;
    const float* inputs = (const float*)d_in[0];
    const int*   ops    = (const int*)d_in[1];
    const float* w_ih   = (const float*)d_in[2];
    const float* w_hh   = (const float*)d_in[3];
    const float* b_ih   = (const float*)d_in[4];
    const float* b_hh   = (const float*)d_in[5];
    float* out = (float*)d_out;

    // ws layout: [0,4096) cons watermark, then tagged u32 ring [D][128][128]
    unsigned* consw = (unsigned*)d_ws;
    unsigned* ring  = (unsigned*)((char*)d_ws + 4096);

    size_t slot_bytes = (size_t)BATCH * HID * sizeof(unsigned);  // 64 KiB
    size_t avail = (ws_size > 4096) ? (ws_size - 4096) / slot_bytes : 4;
    int D = 4;  // protocol needs D >= 4 (lead 3 + publish lag)
    while ((size_t)(D * 2) <= avail && D < T_STEPS) D *= 2;

    hipMemsetAsync(d_ws, 0, 4096, stream);  // zero watermarks
    hipMemsetAsync(d_out, 0, (size_t)out_size * sizeof(float), stream);

    stack_lstm_pipe2<<<dim3(256), dim3(512), 0, stream>>>(
        inputs, ops, w_ih, w_hh, b_ih, b_hh, out, ring, consw, D);
}